// Round 2
// baseline (91.588 us; speedup 1.0000x reference)
//
#include <hip/hip_runtime.h>

// pAUC loss, single-dispatch, REDUNDANT-SELECT version, round 7:
//   bce(i,j) = -log(clip(sigmoid(pos_i - neg_j), 1e-6, 1-1e-6))
//   out = sum_i topk_j(bce, K=512) / (N_pos * N_neg)
// bce monotone in neg_j => every row's top-K = the K largest negatives.
// Every block runs the select locally (identical deterministic result).
// R7 changes vs R6: select restructured from 4 barrier-heavy radix passes
// (~20 __syncthreads) to ONE histogram pass + candidate rank-count:
//  - per-wave (16x) privatized pass-0 histogram, x17-padded layout
//    (conflict-free merge, bank-spread hot-bin atomics).
//  - single-level scan: every wave redundantly suffix-scans wtot[16] in
//    registers (drops one barrier + the wave0-only phase).
//  - threshold-bin candidates (~720 of 16384 for normal data) compacted to
//    LDS in the same sweep that scatters guaranteed top keys; exact in-bin
//    threshold found by brute-force rank-count over broadcast uint4 reads
//    (no barriers, no atomics). Radix passes 1..3 retained only as a
//    fallback when the bin holds > 1024 candidates (adversarial data).
//  - fast path: 8 barriers total vs ~20.

#define TOPK 512
#define BT   1024
#define GRID 256
#define EPT  16                  // BT * EPT = 16384 >= n_neg
#define NHIST 16                 // per-wave privatized pass-0 histograms
#define HPAD  17                 // bank-spread: hist[bin*17 + copy]
#define HWORDS (1024 * HPAD)     // 68 KB
#define CAP   1024               // max candidates for rank-count path
#define POS_LDS 1024
#define BCE_LO 1.0000005e-6f     // -log(1-1e-6)
#define BCE_HI 13.8155106f       // -log(1e-6)

__device__ __forceinline__ float decode_key(unsigned int ky) {
    unsigned int u = (ky >> 31) ? (ky ^ 0x80000000u) : (ky ^ 0xFFFFFFFFu);
    return __uint_as_float(u);
}

__global__ __launch_bounds__(BT) void pauc_fused_kernel(
    const float* __restrict__ neg, int n_neg,
    const float* __restrict__ pos, int n_pos,
    float* __restrict__ out, float inv_denom, int k,
    float* __restrict__ partials, unsigned int* __restrict__ done) {
    const int tid  = threadIdx.x;
    const int lane = tid & 63;
    const int wv   = tid >> 6;

    __shared__ __align__(16) unsigned int hist[HWORDS];  // 68 KB; reused as cand buf
    __shared__ float        s_topk[TOPK];
    __shared__ float        s_pos[POS_LDS];
    __shared__ unsigned int wtot[16];
    __shared__ unsigned int bc_digit, bc_kk, bc_cd;
    __shared__ unsigned int out_gt, out_cd;
    __shared__ unsigned int sh_T, sh_g2;
    __shared__ float        s_red[BT / 64];

    const int rows_pb = (n_pos + GRID - 1) / GRID;      // 32 in harness
    const bool pos_in_lds = rows_pb <= POS_LDS;

    // -------- issue pos prefetch FIRST (latency hides under select) --------
    float pv0 = 0.0f;
    const int prow = blockIdx.x * rows_pb + tid;
    const bool pv0_v = pos_in_lds && (tid < rows_pb) && (prow < n_pos);
    if (pv0_v) pv0 = pos[prow];

    // ---------------- load all keys (every block, redundant) ----------------
    unsigned int keys[EPT];
    if (n_neg == BT * EPT) {                // harness case: float4 loads
        const float4* n4 = (const float4*)neg;
        #pragma unroll
        for (int t = 0; t < EPT / 4; ++t) {
            float4 v = n4[t * BT + tid];
            unsigned int u0 = __float_as_uint(v.x), u1 = __float_as_uint(v.y);
            unsigned int u2 = __float_as_uint(v.z), u3 = __float_as_uint(v.w);
            keys[4*t+0] = u0 ^ (0x80000000u | (unsigned)((int)u0 >> 31));
            keys[4*t+1] = u1 ^ (0x80000000u | (unsigned)((int)u1 >> 31));
            keys[4*t+2] = u2 ^ (0x80000000u | (unsigned)((int)u2 >> 31));
            keys[4*t+3] = u3 ^ (0x80000000u | (unsigned)((int)u3 >> 31));
        }
    } else {
        #pragma unroll
        for (int t = 0; t < EPT; ++t) {
            int i = t * BT + tid;
            unsigned int key = 0u;          // pad = smallest key
            if (i < n_neg) {
                unsigned int u = __float_as_uint(neg[i]);
                key = u ^ (0x80000000u | (unsigned)((int)u >> 31));
            }
            keys[t] = key;
        }
    }

    // zero histograms + counters
    #pragma unroll
    for (int i = 0; i < HPAD; ++i) hist[i * 1024 + tid] = 0u;
    if (tid == 0) { out_gt = 0u; out_cd = 0u; }
    if (pos_in_lds && tid < rows_pb) s_pos[tid] = pv0_v ? pv0 : 0.0f;
    __syncthreads();                                            // B1

    // ---------------- pass 0: per-wave privatized 10-bit histogram ----------
    #pragma unroll
    for (int t = 0; t < EPT; ++t)
        atomicAdd(&hist[(keys[t] >> 22) * HPAD + (unsigned)wv], 1u);
    __syncthreads();                                            // B2

    // merge 16 copies (x17 pad -> conflict-free) + wave suffix scan
    unsigned int c = 0u;
    {
        const unsigned int base = (unsigned)tid * HPAD;
        #pragma unroll
        for (int i = 0; i < NHIST; ++i) c += hist[base + i];
    }
    unsigned int part = c;
    #pragma unroll
    for (int off = 1; off < 64; off <<= 1) {
        unsigned int v = __shfl_down(part, off, 64);
        if (lane + off < 64) part += v;
    }
    if (lane == 0) wtot[wv] = part;
    __syncthreads();                                            // B3
    // every wave redundantly suffix-scans the 16 wave totals (registers)
    unsigned int wsuf = 0u;
    #pragma unroll
    for (int w = 0; w < 16; ++w) wsuf += (w > wv) ? wtot[w] : 0u;
    const unsigned int k0 = (unsigned)k;
    unsigned int suf = part + wsuf;
    unsigned int s_next = __shfl_down(suf, 1, 64);
    if (lane == 63) s_next = wsuf;
    if (suf >= k0 && s_next < k0) {
        bc_digit = (unsigned)tid;
        bc_kk    = k0 - s_next;              // needed from chosen bin
        bc_cd    = c;                        // chosen bin's count
    }
    __syncthreads();                                            // B4

    const unsigned int B  = bc_digit;
    unsigned int kkv      = bc_kk;
    const unsigned int cd = bc_cd;

    if (cd <= CAP) {
        // =================== FAST PATH: rank-count in bin B ================
        unsigned int* s_cand = hist;         // histogram is dead past B4
        if (tid < 4) s_cand[cd + tid] = 0u;  // zero-pad for uint4 rank loop
        // one sweep: scatter guaranteed top keys (bin > B), compact bin == B
        #pragma unroll
        for (int t = 0; t < EPT; ++t) {
            unsigned int ky  = keys[t];
            unsigned int bin = ky >> 22;
            bool g = bin > B;
            unsigned long long m = __ballot(g);
            if (m) {
                unsigned int cnt = (unsigned)__popcll(m);
                unsigned int base;
                if (lane == 0) base = atomicAdd(&out_gt, cnt);
                base = __shfl(base, 0, 64);
                if (g) {
                    unsigned int idx = base +
                        (unsigned)__popcll(m & ((1ull << lane) - 1ull));
                    s_topk[idx] = decode_key(ky);
                }
            }
            bool e = (bin == B);
            unsigned long long me = __ballot(e);
            if (me) {
                unsigned int cnt = (unsigned)__popcll(me);
                unsigned int base;
                if (lane == 0) base = atomicAdd(&out_cd, cnt);
                base = __shfl(base, 0, 64);
                if (e) {
                    unsigned int idx = base +
                        (unsigned)__popcll(me & ((1ull << lane) - 1ull));
                    s_cand[idx] = ky;
                }
            }
        }
        __syncthreads();                                        // B5

        unsigned int Tkey = 0u, g2 = 0u;
        const bool all_sel = (kkv == cd);    // whole bin selected
        unsigned int x = (tid < (int)cd) ? s_cand[tid] : 0u;
        if (!all_sel) {
            // rank-count: gt = #cand > x, ge = #cand >= x (broadcast reads;
            // zero-pad is safe: pads never raise gt, and for x==0 ge>=kkv
            // holds regardless since all candidates >= 0)
            unsigned int gt = 0u, ge = 0u;
            const uint4* c4 = (const uint4*)s_cand;
            const int nq = (int)((cd + 3u) >> 2);
            for (int j = 0; j < nq; ++j) {
                uint4 y = c4[j];
                gt += (unsigned)(y.x > x) + (unsigned)(y.y > x)
                    + (unsigned)(y.z > x) + (unsigned)(y.w > x);
                ge += (unsigned)(y.x >= x) + (unsigned)(y.y >= x)
                    + (unsigned)(y.z >= x) + (unsigned)(y.w >= x);
            }
            // x == T iff gt < kkv <= ge; all matching threads hold equal x
            if (tid < (int)cd && gt < kkv && ge >= kkv) { sh_T = x; sh_g2 = gt; }
            __syncthreads();                                    // B6
            Tkey = sh_T; g2 = sh_g2;
        }
        // scatter selected candidates (> T, or all if whole bin)
        bool sel = (tid < (int)cd) && (all_sel || x > Tkey);
        unsigned long long m = __ballot(sel);
        if (m) {
            unsigned int cnt = (unsigned)__popcll(m);
            unsigned int base;
            if (lane == 0) base = atomicAdd(&out_gt, cnt);
            base = __shfl(base, 0, 64);
            if (sel) {
                unsigned int idx = base +
                    (unsigned)__popcll(m & ((1ull << lane) - 1ull));
                s_topk[idx] = decode_key(x);
            }
        }
        const unsigned int n_tie = all_sel ? 0u : (kkv - g2);
        if ((unsigned)tid < n_tie)
            s_topk[k0 - n_tie + tid] = decode_key(Tkey);
    } else {
        // ============ FALLBACK: classic radix passes on low 22 bits ========
        unsigned int prefix = B << 22;
        unsigned int pmask  = 0xFFC00000u;
        const int      shifts2[3] = {12, 2, 0};
        const unsigned nbv2[3]    = {1024u, 1024u, 4u};
        for (int pass = 0; pass < 3; ++pass) {
            const int shift      = shifts2[pass];
            const unsigned nb    = nbv2[pass];
            const unsigned dmask = nb - 1u;
            if (tid < (int)nb) hist[tid] = 0u;
            __syncthreads();
            #pragma unroll
            for (int t = 0; t < EPT; ++t) {
                unsigned int ky = keys[t];
                if ((ky & pmask) == prefix)
                    atomicAdd(&hist[(ky >> shift) & dmask], 1u);
            }
            __syncthreads();
            unsigned int cc = (tid < (int)nb) ? hist[tid] : 0u;
            unsigned int p2 = cc;
            #pragma unroll
            for (int off = 1; off < 64; off <<= 1) {
                unsigned int v = __shfl_down(p2, off, 64);
                if (lane + off < 64) p2 += v;
            }
            if (lane == 0) wtot[wv] = p2;
            __syncthreads();
            unsigned int ws2 = 0u;
            #pragma unroll
            for (int w = 0; w < 16; ++w) ws2 += (w > wv) ? wtot[w] : 0u;
            unsigned int sf = p2 + ws2;
            unsigned int sn = __shfl_down(sf, 1, 64);
            if (lane == 63) sn = ws2;
            if (tid < (int)nb && sf >= kkv && sn < kkv) {
                bc_digit = (unsigned)tid;
                bc_kk    = kkv - sn;
                bc_cd    = cc;
            }
            __syncthreads();
            unsigned int newpref = prefix | (bc_digit << shift);
            if (pass < 2 && bc_kk == bc_cd && newpref != 0u) {
                prefix = newpref - 1u;       // whole bin: T below bin, no ties
                kkv = 0u;
                break;
            }
            prefix = newpref;
            kkv = bc_kk;
            pmask |= dmask << shift;
        }
        const unsigned int T = prefix;
        #pragma unroll
        for (int t = 0; t < EPT; ++t) {
            unsigned int ky = keys[t];
            bool g = ky > T;
            unsigned long long m = __ballot(g);
            if (m) {
                unsigned int cnt = (unsigned)__popcll(m);
                unsigned int base;
                if (lane == 0) base = atomicAdd(&out_gt, cnt);
                base = __shfl(base, 0, 64);
                if (g) {
                    unsigned int idx = base +
                        (unsigned)__popcll(m & ((1ull << lane) - 1ull));
                    s_topk[idx] = decode_key(ky);
                }
            }
        }
        if ((unsigned)tid < kkv)
            s_topk[(k0 - kkv) + tid] = decode_key(T);
    }
    __syncthreads();                                            // B7

    // -------- bce partial sum: 1 col/thread, 2 row-groups from LDS ----------
    const int col = tid & (TOPK - 1);
    const int rg  = tid >> 9;                          // 0 or 1
    const bool cv = col < k;
    const float tv = cv ? s_topk[col] : 0.0f;
    const int rpg  = (rows_pb + (BT / TOPK) - 1) / (BT / TOPK);  // 16
    const int rbase = blockIdx.x * rows_pb + rg * rpg;
    int lim = n_pos - rbase;
    int lmax = rows_pb - rg * rpg;
    if (lim > lmax) lim = lmax;
    if (lim > rpg)  lim = rpg;
    if (lim < 0)    lim = 0;
    float acc = 0.0f;
    if (pos_in_lds) {
        const float* sp = &s_pos[rg * rpg];
        #pragma unroll 4
        for (int r = 0; r < lim; ++r) {
            float pv = sp[r];
            // -log(clip(sigmoid(pv - tv))) = clamp(log(1 + exp(tv - pv)))
            float b = __logf(1.0f + __expf(tv - pv));
            b = fminf(fmaxf(b, BCE_LO), BCE_HI);
            acc += b;
        }
    } else {
        for (int r = 0; r < lim; ++r) {
            float pv = pos[rbase + r];
            float b = __logf(1.0f + __expf(tv - pv));
            b = fminf(fmaxf(b, BCE_LO), BCE_HI);
            acc += b;
        }
    }
    if (!cv) acc = 0.0f;
    #pragma unroll
    for (int off = 32; off > 0; off >>= 1) acc += __shfl_down(acc, off, 64);
    if (lane == 0) s_red[wv] = acc;
    __syncthreads();                                            // B8
    if (tid == 0) {
        float t = 0.0f;
        #pragma unroll
        for (int w = 0; w < BT / 64; ++w) t += s_red[w];
        __hip_atomic_store(&partials[blockIdx.x], t,
                           __ATOMIC_RELAXED, __HIP_MEMORY_SCOPE_AGENT);
        __hip_atomic_store(&done[blockIdx.x], 1u,
                           __ATOMIC_RELEASE, __HIP_MEMORY_SCOPE_AGENT);
    }

    // ---------------- block 0: gather the 256 partials ----------------------
    if (blockIdx.x == 0) {
        float a = 0.0f;
        if (tid < GRID) {
            while (__hip_atomic_load(&done[tid], __ATOMIC_RELAXED,
                                     __HIP_MEMORY_SCOPE_AGENT) != 1u)
                __builtin_amdgcn_s_sleep(1);
            __builtin_amdgcn_fence(__ATOMIC_ACQUIRE, "agent");
            a = __hip_atomic_load(&partials[tid], __ATOMIC_RELAXED,
                                  __HIP_MEMORY_SCOPE_AGENT);
        }
        #pragma unroll
        for (int off = 32; off > 0; off >>= 1) a += __shfl_down(a, off, 64);
        if (lane == 0) s_red[wv] = a;
        __syncthreads();
        if (tid == 0) {
            float t = 0.0f;
            #pragma unroll
            for (int w = 0; w < BT / 64; ++w) t += s_red[w];
            out[0] = t * inv_denom;
        }
    }
}

extern "C" void kernel_launch(void* const* d_in, const int* in_sizes, int n_in,
                              void* d_out, int out_size, void* d_ws, size_t ws_size,
                              hipStream_t stream) {
    const float* neg = (const float*)d_in[0];   // score_neg, 16384
    const float* pos = (const float*)d_in[1];   // score_pos, 8192
    const int n_neg = in_sizes[0];
    const int n_pos = in_sizes[1];
    float* out = (float*)d_out;
    float* ws  = (float*)d_ws;

    int k = TOPK; if (k > n_neg) k = n_neg;
    float*        partials = ws;                             // [0, GRID)
    unsigned int* done     = (unsigned int*)(ws + GRID);     // [GRID, 2*GRID)

    const float inv_denom = (float)(1.0 / ((double)n_pos * (double)n_neg));
    pauc_fused_kernel<<<GRID, BT, 0, stream>>>(
        neg, n_neg, pos, n_pos, out, inv_denom, k, partials, done);
}

// Round 3
// 90.643 us; speedup vs baseline: 1.0104x; 1.0104x over previous
//
#include <hip/hip_runtime.h>

// pAUC loss, single-dispatch, REDUNDANT-SELECT version, round 8:
//   bce(i,j) = -log(clip(sigmoid(pos_i - neg_j), 1e-6, 1-1e-6))
//   out = sum_i topk_j(bce, K=512) / (N_pos * N_neg)
// bce monotone in neg_j => every row's top-K = the K largest negatives.
// Every block runs the select locally (identical deterministic result).
//
// R8 change vs R7 (single, surgical): __launch_bounds__(BT, 4).
// R7's counters showed VGPR_Count=32 -- impossible with keys[16] live in
// registers. The compiler's occupancy heuristic (74.5 KB LDS allows 2
// WGs/CU -> it targeted 8 waves/SIMD -> <=64 VGPRs) evicted keys[] to
// scratch/rematerialization, turning every key touch in all three sweeps
// into a memory round-trip (kernel measured 42.5 us vs ~8 us modeled).
// Declaring 4 waves/EU (exactly our 1-WG/CU launch; grid=256=#CUs) grants
// the allocator the full 128-VGPR budget so keys stay register-resident.

#define TOPK 512
#define BT   1024
#define GRID 256
#define EPT  16                  // BT * EPT = 16384 >= n_neg
#define NHIST 16                 // per-wave privatized pass-0 histograms
#define HPAD  17                 // bank-spread: hist[bin*17 + copy]
#define HWORDS (1024 * HPAD)     // 68 KB
#define CAP   1024               // max candidates for rank-count path
#define POS_LDS 1024
#define BCE_LO 1.0000005e-6f     // -log(1-1e-6)
#define BCE_HI 13.8155106f       // -log(1e-6)

__device__ __forceinline__ float decode_key(unsigned int ky) {
    unsigned int u = (ky >> 31) ? (ky ^ 0x80000000u) : (ky ^ 0xFFFFFFFFu);
    return __uint_as_float(u);
}

__global__ __launch_bounds__(BT, 4) void pauc_fused_kernel(
    const float* __restrict__ neg, int n_neg,
    const float* __restrict__ pos, int n_pos,
    float* __restrict__ out, float inv_denom, int k,
    float* __restrict__ partials, unsigned int* __restrict__ done) {
    const int tid  = threadIdx.x;
    const int lane = tid & 63;
    const int wv   = tid >> 6;

    __shared__ __align__(16) unsigned int hist[HWORDS];  // 68 KB; reused as cand buf
    __shared__ float        s_topk[TOPK];
    __shared__ float        s_pos[POS_LDS];
    __shared__ unsigned int wtot[16];
    __shared__ unsigned int bc_digit, bc_kk, bc_cd;
    __shared__ unsigned int out_gt, out_cd;
    __shared__ unsigned int sh_T, sh_g2;
    __shared__ float        s_red[BT / 64];

    const int rows_pb = (n_pos + GRID - 1) / GRID;      // 32 in harness
    const bool pos_in_lds = rows_pb <= POS_LDS;

    // -------- issue pos prefetch FIRST (latency hides under select) --------
    float pv0 = 0.0f;
    const int prow = blockIdx.x * rows_pb + tid;
    const bool pv0_v = pos_in_lds && (tid < rows_pb) && (prow < n_pos);
    if (pv0_v) pv0 = pos[prow];

    // ---------------- load all keys (every block, redundant) ----------------
    unsigned int keys[EPT];
    if (n_neg == BT * EPT) {                // harness case: float4 loads
        const float4* n4 = (const float4*)neg;
        #pragma unroll
        for (int t = 0; t < EPT / 4; ++t) {
            float4 v = n4[t * BT + tid];
            unsigned int u0 = __float_as_uint(v.x), u1 = __float_as_uint(v.y);
            unsigned int u2 = __float_as_uint(v.z), u3 = __float_as_uint(v.w);
            keys[4*t+0] = u0 ^ (0x80000000u | (unsigned)((int)u0 >> 31));
            keys[4*t+1] = u1 ^ (0x80000000u | (unsigned)((int)u1 >> 31));
            keys[4*t+2] = u2 ^ (0x80000000u | (unsigned)((int)u2 >> 31));
            keys[4*t+3] = u3 ^ (0x80000000u | (unsigned)((int)u3 >> 31));
        }
    } else {
        #pragma unroll
        for (int t = 0; t < EPT; ++t) {
            int i = t * BT + tid;
            unsigned int key = 0u;          // pad = smallest key
            if (i < n_neg) {
                unsigned int u = __float_as_uint(neg[i]);
                key = u ^ (0x80000000u | (unsigned)((int)u >> 31));
            }
            keys[t] = key;
        }
    }

    // zero histograms + counters
    #pragma unroll
    for (int i = 0; i < HPAD; ++i) hist[i * 1024 + tid] = 0u;
    if (tid == 0) { out_gt = 0u; out_cd = 0u; }
    if (pos_in_lds && tid < rows_pb) s_pos[tid] = pv0_v ? pv0 : 0.0f;
    __syncthreads();                                            // B1

    // ---------------- pass 0: per-wave privatized 10-bit histogram ----------
    #pragma unroll
    for (int t = 0; t < EPT; ++t)
        atomicAdd(&hist[(keys[t] >> 22) * HPAD + (unsigned)wv], 1u);
    __syncthreads();                                            // B2

    // merge 16 copies (x17 pad -> conflict-free) + wave suffix scan
    unsigned int c = 0u;
    {
        const unsigned int base = (unsigned)tid * HPAD;
        #pragma unroll
        for (int i = 0; i < NHIST; ++i) c += hist[base + i];
    }
    unsigned int part = c;
    #pragma unroll
    for (int off = 1; off < 64; off <<= 1) {
        unsigned int v = __shfl_down(part, off, 64);
        if (lane + off < 64) part += v;
    }
    if (lane == 0) wtot[wv] = part;
    __syncthreads();                                            // B3
    // every wave redundantly suffix-scans the 16 wave totals (registers)
    unsigned int wsuf = 0u;
    #pragma unroll
    for (int w = 0; w < 16; ++w) wsuf += (w > wv) ? wtot[w] : 0u;
    const unsigned int k0 = (unsigned)k;
    unsigned int suf = part + wsuf;
    unsigned int s_next = __shfl_down(suf, 1, 64);
    if (lane == 63) s_next = wsuf;
    if (suf >= k0 && s_next < k0) {
        bc_digit = (unsigned)tid;
        bc_kk    = k0 - s_next;              // needed from chosen bin
        bc_cd    = c;                        // chosen bin's count
    }
    __syncthreads();                                            // B4

    const unsigned int B  = bc_digit;
    unsigned int kkv      = bc_kk;
    const unsigned int cd = bc_cd;

    if (cd <= CAP) {
        // =================== FAST PATH: rank-count in bin B ================
        unsigned int* s_cand = hist;         // histogram is dead past B4
        if (tid < 4) s_cand[cd + tid] = 0u;  // zero-pad for uint4 rank loop
        // one sweep: scatter guaranteed top keys (bin > B), compact bin == B
        #pragma unroll
        for (int t = 0; t < EPT; ++t) {
            unsigned int ky  = keys[t];
            unsigned int bin = ky >> 22;
            bool g = bin > B;
            unsigned long long m = __ballot(g);
            if (m) {
                unsigned int cnt = (unsigned)__popcll(m);
                unsigned int base;
                if (lane == 0) base = atomicAdd(&out_gt, cnt);
                base = __shfl(base, 0, 64);
                if (g) {
                    unsigned int idx = base +
                        (unsigned)__popcll(m & ((1ull << lane) - 1ull));
                    s_topk[idx] = decode_key(ky);
                }
            }
            bool e = (bin == B);
            unsigned long long me = __ballot(e);
            if (me) {
                unsigned int cnt = (unsigned)__popcll(me);
                unsigned int base;
                if (lane == 0) base = atomicAdd(&out_cd, cnt);
                base = __shfl(base, 0, 64);
                if (e) {
                    unsigned int idx = base +
                        (unsigned)__popcll(me & ((1ull << lane) - 1ull));
                    s_cand[idx] = ky;
                }
            }
        }
        __syncthreads();                                        // B5

        unsigned int Tkey = 0u, g2 = 0u;
        const bool all_sel = (kkv == cd);    // whole bin selected
        unsigned int x = (tid < (int)cd) ? s_cand[tid] : 0u;
        if (!all_sel) {
            // rank-count: gt = #cand > x, ge = #cand >= x (broadcast reads;
            // zero-pad is safe: pads never raise gt, and for x==0 ge>=kkv
            // holds regardless since all candidates >= 0)
            unsigned int gt = 0u, ge = 0u;
            const uint4* c4 = (const uint4*)s_cand;
            const int nq = (int)((cd + 3u) >> 2);
            for (int j = 0; j < nq; ++j) {
                uint4 y = c4[j];
                gt += (unsigned)(y.x > x) + (unsigned)(y.y > x)
                    + (unsigned)(y.z > x) + (unsigned)(y.w > x);
                ge += (unsigned)(y.x >= x) + (unsigned)(y.y >= x)
                    + (unsigned)(y.z >= x) + (unsigned)(y.w >= x);
            }
            // x == T iff gt < kkv <= ge; all matching threads hold equal x
            if (tid < (int)cd && gt < kkv && ge >= kkv) { sh_T = x; sh_g2 = gt; }
            __syncthreads();                                    // B6
            Tkey = sh_T; g2 = sh_g2;
        }
        // scatter selected candidates (> T, or all if whole bin)
        bool sel = (tid < (int)cd) && (all_sel || x > Tkey);
        unsigned long long m = __ballot(sel);
        if (m) {
            unsigned int cnt = (unsigned)__popcll(m);
            unsigned int base;
            if (lane == 0) base = atomicAdd(&out_gt, cnt);
            base = __shfl(base, 0, 64);
            if (sel) {
                unsigned int idx = base +
                    (unsigned)__popcll(m & ((1ull << lane) - 1ull));
                s_topk[idx] = decode_key(x);
            }
        }
        const unsigned int n_tie = all_sel ? 0u : (kkv - g2);
        if ((unsigned)tid < n_tie)
            s_topk[k0 - n_tie + tid] = decode_key(Tkey);
    } else {
        // ============ FALLBACK: classic radix passes on low 22 bits ========
        unsigned int prefix = B << 22;
        unsigned int pmask  = 0xFFC00000u;
        const int      shifts2[3] = {12, 2, 0};
        const unsigned nbv2[3]    = {1024u, 1024u, 4u};
        for (int pass = 0; pass < 3; ++pass) {
            const int shift      = shifts2[pass];
            const unsigned nb    = nbv2[pass];
            const unsigned dmask = nb - 1u;
            if (tid < (int)nb) hist[tid] = 0u;
            __syncthreads();
            #pragma unroll
            for (int t = 0; t < EPT; ++t) {
                unsigned int ky = keys[t];
                if ((ky & pmask) == prefix)
                    atomicAdd(&hist[(ky >> shift) & dmask], 1u);
            }
            __syncthreads();
            unsigned int cc = (tid < (int)nb) ? hist[tid] : 0u;
            unsigned int p2 = cc;
            #pragma unroll
            for (int off = 1; off < 64; off <<= 1) {
                unsigned int v = __shfl_down(p2, off, 64);
                if (lane + off < 64) p2 += v;
            }
            if (lane == 0) wtot[wv] = p2;
            __syncthreads();
            unsigned int ws2 = 0u;
            #pragma unroll
            for (int w = 0; w < 16; ++w) ws2 += (w > wv) ? wtot[w] : 0u;
            unsigned int sf = p2 + ws2;
            unsigned int sn = __shfl_down(sf, 1, 64);
            if (lane == 63) sn = ws2;
            if (tid < (int)nb && sf >= kkv && sn < kkv) {
                bc_digit = (unsigned)tid;
                bc_kk    = kkv - sn;
                bc_cd    = cc;
            }
            __syncthreads();
            unsigned int newpref = prefix | (bc_digit << shift);
            if (pass < 2 && bc_kk == bc_cd && newpref != 0u) {
                prefix = newpref - 1u;       // whole bin: T below bin, no ties
                kkv = 0u;
                break;
            }
            prefix = newpref;
            kkv = bc_kk;
            pmask |= dmask << shift;
        }
        const unsigned int T = prefix;
        #pragma unroll
        for (int t = 0; t < EPT; ++t) {
            unsigned int ky = keys[t];
            bool g = ky > T;
            unsigned long long m = __ballot(g);
            if (m) {
                unsigned int cnt = (unsigned)__popcll(m);
                unsigned int base;
                if (lane == 0) base = atomicAdd(&out_gt, cnt);
                base = __shfl(base, 0, 64);
                if (g) {
                    unsigned int idx = base +
                        (unsigned)__popcll(m & ((1ull << lane) - 1ull));
                    s_topk[idx] = decode_key(ky);
                }
            }
        }
        if ((unsigned)tid < kkv)
            s_topk[(k0 - kkv) + tid] = decode_key(T);
    }
    __syncthreads();                                            // B7

    // -------- bce partial sum: 1 col/thread, 2 row-groups from LDS ----------
    const int col = tid & (TOPK - 1);
    const int rg  = tid >> 9;                          // 0 or 1
    const bool cv = col < k;
    const float tv = cv ? s_topk[col] : 0.0f;
    const int rpg  = (rows_pb + (BT / TOPK) - 1) / (BT / TOPK);  // 16
    const int rbase = blockIdx.x * rows_pb + rg * rpg;
    int lim = n_pos - rbase;
    int lmax = rows_pb - rg * rpg;
    if (lim > lmax) lim = lmax;
    if (lim > rpg)  lim = rpg;
    if (lim < 0)    lim = 0;
    float acc = 0.0f;
    if (pos_in_lds) {
        const float* sp = &s_pos[rg * rpg];
        #pragma unroll 4
        for (int r = 0; r < lim; ++r) {
            float pv = sp[r];
            // -log(clip(sigmoid(pv - tv))) = clamp(log(1 + exp(tv - pv)))
            float b = __logf(1.0f + __expf(tv - pv));
            b = fminf(fmaxf(b, BCE_LO), BCE_HI);
            acc += b;
        }
    } else {
        for (int r = 0; r < lim; ++r) {
            float pv = pos[rbase + r];
            float b = __logf(1.0f + __expf(tv - pv));
            b = fminf(fmaxf(b, BCE_LO), BCE_HI);
            acc += b;
        }
    }
    if (!cv) acc = 0.0f;
    #pragma unroll
    for (int off = 32; off > 0; off >>= 1) acc += __shfl_down(acc, off, 64);
    if (lane == 0) s_red[wv] = acc;
    __syncthreads();                                            // B8
    if (tid == 0) {
        float t = 0.0f;
        #pragma unroll
        for (int w = 0; w < BT / 64; ++w) t += s_red[w];
        __hip_atomic_store(&partials[blockIdx.x], t,
                           __ATOMIC_RELAXED, __HIP_MEMORY_SCOPE_AGENT);
        __hip_atomic_store(&done[blockIdx.x], 1u,
                           __ATOMIC_RELEASE, __HIP_MEMORY_SCOPE_AGENT);
    }

    // ---------------- block 0: gather the 256 partials ----------------------
    if (blockIdx.x == 0) {
        float a = 0.0f;
        if (tid < GRID) {
            while (__hip_atomic_load(&done[tid], __ATOMIC_RELAXED,
                                     __HIP_MEMORY_SCOPE_AGENT) != 1u)
                __builtin_amdgcn_s_sleep(1);
            __builtin_amdgcn_fence(__ATOMIC_ACQUIRE, "agent");
            a = __hip_atomic_load(&partials[tid], __ATOMIC_RELAXED,
                                  __HIP_MEMORY_SCOPE_AGENT);
        }
        #pragma unroll
        for (int off = 32; off > 0; off >>= 1) a += __shfl_down(a, off, 64);
        if (lane == 0) s_red[wv] = a;
        __syncthreads();
        if (tid == 0) {
            float t = 0.0f;
            #pragma unroll
            for (int w = 0; w < BT / 64; ++w) t += s_red[w];
            out[0] = t * inv_denom;
        }
    }
}

extern "C" void kernel_launch(void* const* d_in, const int* in_sizes, int n_in,
                              void* d_out, int out_size, void* d_ws, size_t ws_size,
                              hipStream_t stream) {
    const float* neg = (const float*)d_in[0];   // score_neg, 16384
    const float* pos = (const float*)d_in[1];   // score_pos, 8192
    const int n_neg = in_sizes[0];
    const int n_pos = in_sizes[1];
    float* out = (float*)d_out;
    float* ws  = (float*)d_ws;

    int k = TOPK; if (k > n_neg) k = n_neg;
    float*        partials = ws;                             // [0, GRID)
    unsigned int* done     = (unsigned int*)(ws + GRID);     // [GRID, 2*GRID)

    const float inv_denom = (float)(1.0 / ((double)n_pos * (double)n_neg));
    pauc_fused_kernel<<<GRID, BT, 0, stream>>>(
        neg, n_neg, pos, n_pos, out, inv_denom, k, partials, done);
}

// Round 4
// 70.409 us; speedup vs baseline: 1.3008x; 1.2874x over previous
//
#include <hip/hip_runtime.h>

// pAUC loss, single-dispatch, REDUNDANT-SELECT version, round 9:
//   bce(i,j) = -log(clip(sigmoid(pos_i - neg_j), 1e-6, 1-1e-6))
//   out = sum_i topk_j(bce, K=512) / (N_pos * N_neg)
// bce monotone in neg_j => every row's top-K = the K largest negatives.
// Every block runs the select locally (identical deterministic result).
//
// R9 vs R8 (counter-driven): R8 measured VALUBusy=57% -> 24us of VALU issue;
// accounting shows ~17us of it is the O(cd^2) rank-count loop (180 uint4
// iters x ~28 VALU across all 1024 threads) plus ~10us LDS-pipe occupancy.
// Replaced by a SECOND RESTRICTED RADIX PASS: the ~720 compacted candidates
// each do ONE scattered LDS atomic into a fresh 1024-bin histogram of bits
// 12..21 (near-zero conflicts), reuse the same scan, then rank-count only
// the surviving sub-bin (expected 1-3 candidates -> nq~1 instead of 180).
// Also reverted pass-0 to copy-major 8-copy histogram (merge 8 reads, zero
// 8 writes; x17-pad bought nothing - both layouts conflict-free).
// Fallback radix path for cd>1024 (adversarial ties) retained unchanged.

#define TOPK 512
#define BT   1024
#define GRID 256
#define EPT  16                  // BT * EPT = 16384 >= n_neg
#define NHIST 8                  // pass-0 histogram copies (wave pairs)
#define CAP   1024               // max candidates for fast path
#define POS_LDS 1024
#define BCE_LO 1.0000005e-6f     // -log(1-1e-6)
#define BCE_HI 13.8155106f       // -log(1e-6)

__device__ __forceinline__ float decode_key(unsigned int ky) {
    unsigned int u = (ky >> 31) ? (ky ^ 0x80000000u) : (ky ^ 0xFFFFFFFFu);
    return __uint_as_float(u);
}

__global__ __launch_bounds__(BT, 4) void pauc_fused_kernel(
    const float* __restrict__ neg, int n_neg,
    const float* __restrict__ pos, int n_pos,
    float* __restrict__ out, float inv_denom, int k,
    float* __restrict__ partials, unsigned int* __restrict__ done) {
    const int tid  = threadIdx.x;
    const int lane = tid & 63;
    const int wv   = tid >> 6;

    __shared__ __align__(16) unsigned int hist[NHIST * 1024]; // 32 KB; reused as cand buf
    __shared__ __align__(16) unsigned int hist2[1024];        // level-2 histogram
    __shared__ __align__(16) unsigned int cand2[1024 + 4];    // sub-bin candidates (+pad)
    __shared__ float        s_topk[TOPK];
    __shared__ float        s_pos[POS_LDS];
    __shared__ unsigned int wtot[16];
    __shared__ unsigned int bc_digit, bc_kk, bc_cd;
    __shared__ unsigned int out_gt, out_cd, out_cd2;
    __shared__ unsigned int sh_T, sh_g2;
    __shared__ float        s_red[BT / 64];

    const int rows_pb = (n_pos + GRID - 1) / GRID;      // 32 in harness
    const bool pos_in_lds = rows_pb <= POS_LDS;

    // -------- issue pos prefetch FIRST (latency hides under select) --------
    float pv0 = 0.0f;
    const int prow = blockIdx.x * rows_pb + tid;
    const bool pv0_v = pos_in_lds && (tid < rows_pb) && (prow < n_pos);
    if (pv0_v) pv0 = pos[prow];

    // ---------------- load all keys (every block, redundant) ----------------
    unsigned int keys[EPT];
    if (n_neg == BT * EPT) {                // harness case: float4 loads
        const float4* n4 = (const float4*)neg;
        #pragma unroll
        for (int t = 0; t < EPT / 4; ++t) {
            float4 v = n4[t * BT + tid];
            unsigned int u0 = __float_as_uint(v.x), u1 = __float_as_uint(v.y);
            unsigned int u2 = __float_as_uint(v.z), u3 = __float_as_uint(v.w);
            keys[4*t+0] = u0 ^ (0x80000000u | (unsigned)((int)u0 >> 31));
            keys[4*t+1] = u1 ^ (0x80000000u | (unsigned)((int)u1 >> 31));
            keys[4*t+2] = u2 ^ (0x80000000u | (unsigned)((int)u2 >> 31));
            keys[4*t+3] = u3 ^ (0x80000000u | (unsigned)((int)u3 >> 31));
        }
    } else {
        #pragma unroll
        for (int t = 0; t < EPT; ++t) {
            int i = t * BT + tid;
            unsigned int key = 0u;          // pad = smallest key
            if (i < n_neg) {
                unsigned int u = __float_as_uint(neg[i]);
                key = u ^ (0x80000000u | (unsigned)((int)u >> 31));
            }
            keys[t] = key;
        }
    }

    // zero histograms + counters (cand2 zeroed so pad slots are 0)
    #pragma unroll
    for (int i = 0; i < NHIST; ++i) hist[(i << 10) + tid] = 0u;
    hist2[tid] = 0u;
    cand2[tid] = 0u;
    if (tid < 4) cand2[1024 + tid] = 0u;
    if (tid == 0) { out_gt = 0u; out_cd = 0u; out_cd2 = 0u; }
    if (pos_in_lds && tid < rows_pb) s_pos[tid] = pv0_v ? pv0 : 0.0f;
    __syncthreads();                                            // B1

    // ---------------- pass 0: privatized 10-bit histogram (copy/wave-pair) --
    {
        unsigned int* h = &hist[(unsigned)(wv >> 1) << 10];
        #pragma unroll
        for (int t = 0; t < EPT; ++t)
            atomicAdd(&h[keys[t] >> 22], 1u);
    }
    __syncthreads();                                            // B2

    // merge 8 copies (stride-1024: 2 lanes/bank -> free) + wave suffix scan
    unsigned int c = 0u;
    #pragma unroll
    for (int i = 0; i < NHIST; ++i) c += hist[(i << 10) + tid];
    unsigned int part = c;
    #pragma unroll
    for (int off = 1; off < 64; off <<= 1) {
        unsigned int v = __shfl_down(part, off, 64);
        if (lane + off < 64) part += v;
    }
    if (lane == 0) wtot[wv] = part;
    __syncthreads();                                            // B3
    // every wave redundantly suffix-scans the 16 wave totals (registers)
    unsigned int wsuf = 0u;
    #pragma unroll
    for (int w = 0; w < 16; ++w) wsuf += (w > wv) ? wtot[w] : 0u;
    const unsigned int k0 = (unsigned)k;
    unsigned int suf = part + wsuf;
    unsigned int s_next = __shfl_down(suf, 1, 64);
    if (lane == 63) s_next = wsuf;
    if (suf >= k0 && s_next < k0) {
        bc_digit = (unsigned)tid;
        bc_kk    = k0 - s_next;              // needed from chosen bin
        bc_cd    = c;                        // chosen bin's count
    }
    __syncthreads();                                            // B4

    const unsigned int B  = bc_digit;
    unsigned int kkv      = bc_kk;
    const unsigned int cd = bc_cd;

    if (cd <= CAP) {
        // ========== FAST PATH: restricted level-2 radix on candidates ======
        unsigned int* s_cand = hist;         // histogram is dead past B4
        // one sweep: scatter guaranteed top keys (bin > B), compact bin == B
        #pragma unroll
        for (int t = 0; t < EPT; ++t) {
            unsigned int ky  = keys[t];
            unsigned int bin = ky >> 22;
            bool g = bin > B;
            unsigned long long m = __ballot(g);
            if (m) {
                unsigned int cnt = (unsigned)__popcll(m);
                unsigned int base;
                if (lane == 0) base = atomicAdd(&out_gt, cnt);
                base = __shfl(base, 0, 64);
                if (g) {
                    unsigned int idx = base +
                        (unsigned)__popcll(m & ((1ull << lane) - 1ull));
                    s_topk[idx] = decode_key(ky);
                }
            }
            bool e = (bin == B);
            unsigned long long me = __ballot(e);
            if (me) {
                unsigned int cnt = (unsigned)__popcll(me);
                unsigned int base;
                if (lane == 0) base = atomicAdd(&out_cd, cnt);
                base = __shfl(base, 0, 64);
                if (e) {
                    unsigned int idx = base +
                        (unsigned)__popcll(me & ((1ull << lane) - 1ull));
                    s_cand[idx] = ky;
                }
            }
        }
        __syncthreads();                                        // B5

        unsigned int Tkey = 0u;
        unsigned int n_tie = 0u;
        const bool all_sel = (kkv == cd);    // whole bin selected
        unsigned int x = (tid < (int)cd) ? s_cand[tid] : 0u;
        if (!all_sel) {
            // ---- level-2 histogram of bits 12..21 over the candidates ----
            // ~cd (<=1024) single atomics scattered over 1024 bins: ~0 conflicts
            if (tid < (int)cd)
                atomicAdd(&hist2[(x >> 12) & 1023u], 1u);
            __syncthreads();                                    // B6
            unsigned int c2 = hist2[tid];
            unsigned int p2 = c2;
            #pragma unroll
            for (int off = 1; off < 64; off <<= 1) {
                unsigned int v = __shfl_down(p2, off, 64);
                if (lane + off < 64) p2 += v;
            }
            if (lane == 0) wtot[wv] = p2;
            __syncthreads();                                    // B7
            unsigned int ws2 = 0u;
            #pragma unroll
            for (int w = 0; w < 16; ++w) ws2 += (w > wv) ? wtot[w] : 0u;
            unsigned int sf2 = p2 + ws2;
            unsigned int sn2 = __shfl_down(sf2, 1, 64);
            if (lane == 63) sn2 = ws2;
            if (sf2 >= kkv && sn2 < kkv) {
                bc_digit = (unsigned)tid;    // reuse (level-1 values consumed)
                bc_kk    = kkv - sn2;
                bc_cd    = c2;
            }
            __syncthreads();                                    // B8
            const unsigned int B2   = bc_digit;
            const unsigned int kkv2 = bc_kk;
            const unsigned int cd2  = bc_cd;
            const bool all2 = (kkv2 == cd2);
            if (!all2) {
                // compact sub-bin candidates (expected 1-3, bounded by cd)
                bool e2 = (tid < (int)cd) && (((x >> 12) & 1023u) == B2);
                unsigned long long m2 = __ballot(e2);
                if (m2) {
                    unsigned int cnt = (unsigned)__popcll(m2);
                    unsigned int base;
                    if (lane == 0) base = atomicAdd(&out_cd2, cnt);
                    base = __shfl(base, 0, 64);
                    if (e2) {
                        unsigned int idx = base +
                            (unsigned)__popcll(m2 & ((1ull << lane) - 1ull));
                        cand2[idx] = x;
                    }
                }
                __syncthreads();                                // B9
                // tiny rank-count: gt=#cand2>y, ge=#cand2>=y (broadcast uint4;
                // zero pads never raise gt; participants have y>0)
                unsigned int y = (tid < (int)cd2) ? cand2[tid] : 0u;
                unsigned int gt = 0u, ge = 0u;
                const uint4* c4 = (const uint4*)cand2;
                const int nq = (int)((cd2 + 3u) >> 2);
                for (int j = 0; j < nq; ++j) {
                    uint4 q = c4[j];
                    gt += (unsigned)(q.x > y) + (unsigned)(q.y > y)
                        + (unsigned)(q.z > y) + (unsigned)(q.w > y);
                    ge += (unsigned)(q.x >= y) + (unsigned)(q.y >= y)
                        + (unsigned)(q.z >= y) + (unsigned)(q.w >= y);
                }
                if (tid < (int)cd2 && gt < kkv2 && ge >= kkv2) {
                    sh_T = y; sh_g2 = gt;
                }
                __syncthreads();                                // B10
                Tkey  = sh_T;
                n_tie = kkv2 - sh_g2;
            } else {
                // whole sub-bin selected: T just below sub-bin, no ties.
                // (B,B2)==(0,0) with all2 is impossible: that would imply
                // kkv==cd, handled by all_sel.
                Tkey  = ((B << 22) | (B2 << 12)) - 1u;
                n_tie = 0u;
            }
        }
        // scatter selected candidates (> T, or all if whole bin)
        bool sel = (tid < (int)cd) && (all_sel || x > Tkey);
        unsigned long long m = __ballot(sel);
        if (m) {
            unsigned int cnt = (unsigned)__popcll(m);
            unsigned int base;
            if (lane == 0) base = atomicAdd(&out_gt, cnt);
            base = __shfl(base, 0, 64);
            if (sel) {
                unsigned int idx = base +
                    (unsigned)__popcll(m & ((1ull << lane) - 1ull));
                s_topk[idx] = decode_key(x);
            }
        }
        if ((unsigned)tid < n_tie)
            s_topk[k0 - n_tie + tid] = decode_key(Tkey);
    } else {
        // ============ FALLBACK: classic radix passes on low 22 bits ========
        unsigned int prefix = B << 22;
        unsigned int pmask  = 0xFFC00000u;
        const int      shifts2[3] = {12, 2, 0};
        const unsigned nbv2[3]    = {1024u, 1024u, 4u};
        for (int pass = 0; pass < 3; ++pass) {
            const int shift      = shifts2[pass];
            const unsigned nb    = nbv2[pass];
            const unsigned dmask = nb - 1u;
            if (tid < (int)nb) hist[tid] = 0u;
            __syncthreads();
            #pragma unroll
            for (int t = 0; t < EPT; ++t) {
                unsigned int ky = keys[t];
                if ((ky & pmask) == prefix)
                    atomicAdd(&hist[(ky >> shift) & dmask], 1u);
            }
            __syncthreads();
            unsigned int cc = (tid < (int)nb) ? hist[tid] : 0u;
            unsigned int p2 = cc;
            #pragma unroll
            for (int off = 1; off < 64; off <<= 1) {
                unsigned int v = __shfl_down(p2, off, 64);
                if (lane + off < 64) p2 += v;
            }
            if (lane == 0) wtot[wv] = p2;
            __syncthreads();
            unsigned int ws2 = 0u;
            #pragma unroll
            for (int w = 0; w < 16; ++w) ws2 += (w > wv) ? wtot[w] : 0u;
            unsigned int sf = p2 + ws2;
            unsigned int sn = __shfl_down(sf, 1, 64);
            if (lane == 63) sn = ws2;
            if (tid < (int)nb && sf >= kkv && sn < kkv) {
                bc_digit = (unsigned)tid;
                bc_kk    = kkv - sn;
                bc_cd    = cc;
            }
            __syncthreads();
            unsigned int newpref = prefix | (bc_digit << shift);
            if (pass < 2 && bc_kk == bc_cd && newpref != 0u) {
                prefix = newpref - 1u;       // whole bin: T below bin, no ties
                kkv = 0u;
                break;
            }
            prefix = newpref;
            kkv = bc_kk;
            pmask |= dmask << shift;
        }
        const unsigned int T = prefix;
        #pragma unroll
        for (int t = 0; t < EPT; ++t) {
            unsigned int ky = keys[t];
            bool g = ky > T;
            unsigned long long m = __ballot(g);
            if (m) {
                unsigned int cnt = (unsigned)__popcll(m);
                unsigned int base;
                if (lane == 0) base = atomicAdd(&out_gt, cnt);
                base = __shfl(base, 0, 64);
                if (g) {
                    unsigned int idx = base +
                        (unsigned)__popcll(m & ((1ull << lane) - 1ull));
                    s_topk[idx] = decode_key(ky);
                }
            }
        }
        if ((unsigned)tid < kkv)
            s_topk[(k0 - kkv) + tid] = decode_key(T);
    }
    __syncthreads();                                            // B11

    // -------- bce partial sum: 1 col/thread, 2 row-groups from LDS ----------
    const int col = tid & (TOPK - 1);
    const int rg  = tid >> 9;                          // 0 or 1
    const bool cv = col < k;
    const float tv = cv ? s_topk[col] : 0.0f;
    const int rpg  = (rows_pb + (BT / TOPK) - 1) / (BT / TOPK);  // 16
    const int rbase = blockIdx.x * rows_pb + rg * rpg;
    int lim = n_pos - rbase;
    int lmax = rows_pb - rg * rpg;
    if (lim > lmax) lim = lmax;
    if (lim > rpg)  lim = rpg;
    if (lim < 0)    lim = 0;
    float acc = 0.0f;
    if (pos_in_lds) {
        const float* sp = &s_pos[rg * rpg];
        #pragma unroll 4
        for (int r = 0; r < lim; ++r) {
            float pv = sp[r];
            // -log(clip(sigmoid(pv - tv))) = clamp(log(1 + exp(tv - pv)))
            float b = __logf(1.0f + __expf(tv - pv));
            b = fminf(fmaxf(b, BCE_LO), BCE_HI);
            acc += b;
        }
    } else {
        for (int r = 0; r < lim; ++r) {
            float pv = pos[rbase + r];
            float b = __logf(1.0f + __expf(tv - pv));
            b = fminf(fmaxf(b, BCE_LO), BCE_HI);
            acc += b;
        }
    }
    if (!cv) acc = 0.0f;
    #pragma unroll
    for (int off = 32; off > 0; off >>= 1) acc += __shfl_down(acc, off, 64);
    if (lane == 0) s_red[wv] = acc;
    __syncthreads();                                            // B12
    if (tid == 0) {
        float t = 0.0f;
        #pragma unroll
        for (int w = 0; w < BT / 64; ++w) t += s_red[w];
        __hip_atomic_store(&partials[blockIdx.x], t,
                           __ATOMIC_RELAXED, __HIP_MEMORY_SCOPE_AGENT);
        __hip_atomic_store(&done[blockIdx.x], 1u,
                           __ATOMIC_RELEASE, __HIP_MEMORY_SCOPE_AGENT);
    }

    // ---------------- block 0: gather the 256 partials ----------------------
    if (blockIdx.x == 0) {
        float a = 0.0f;
        if (tid < GRID) {
            while (__hip_atomic_load(&done[tid], __ATOMIC_RELAXED,
                                     __HIP_MEMORY_SCOPE_AGENT) != 1u)
                __builtin_amdgcn_s_sleep(1);
            __builtin_amdgcn_fence(__ATOMIC_ACQUIRE, "agent");
            a = __hip_atomic_load(&partials[tid], __ATOMIC_RELAXED,
                                  __HIP_MEMORY_SCOPE_AGENT);
        }
        #pragma unroll
        for (int off = 32; off > 0; off >>= 1) a += __shfl_down(a, off, 64);
        if (lane == 0) s_red[wv] = a;
        __syncthreads();
        if (tid == 0) {
            float t = 0.0f;
            #pragma unroll
            for (int w = 0; w < BT / 64; ++w) t += s_red[w];
            out[0] = t * inv_denom;
        }
    }
}

extern "C" void kernel_launch(void* const* d_in, const int* in_sizes, int n_in,
                              void* d_out, int out_size, void* d_ws, size_t ws_size,
                              hipStream_t stream) {
    const float* neg = (const float*)d_in[0];   // score_neg, 16384
    const float* pos = (const float*)d_in[1];   // score_pos, 8192
    const int n_neg = in_sizes[0];
    const int n_pos = in_sizes[1];
    float* out = (float*)d_out;
    float* ws  = (float*)d_ws;

    int k = TOPK; if (k > n_neg) k = n_neg;
    float*        partials = ws;                             // [0, GRID)
    unsigned int* done     = (unsigned int*)(ws + GRID);     // [GRID, 2*GRID)

    const float inv_denom = (float)(1.0 / ((double)n_pos * (double)n_neg));
    pauc_fused_kernel<<<GRID, BT, 0, stream>>>(
        neg, n_neg, pos, n_pos, out, inv_denom, k, partials, done);
}

// Round 5
// 70.067 us; speedup vs baseline: 1.3071x; 1.0049x over previous
//
#include <hip/hip_runtime.h>

// pAUC loss, single-dispatch, REDUNDANT-SELECT version, round 10:
//   bce(i,j) = -log(clip(sigmoid(pos_i - neg_j), 1e-6, 1-1e-6))
//   out = sum_i topk_j(bce, K=512) / (N_pos * N_neg)
// bce monotone in neg_j => every row's top-K = the K largest negatives.
// Every block runs the select locally (identical deterministic result).
//
// R10 vs R9 (chain-driven): R9 ~21.5us vs R6 ~18.7us despite fewer barriers
// -> cost is NOT barriers; it is the per-key-slot dependent LDS chains
// (lane0 atomicAdd -> shfl broadcast -> scatter, ~200-300cy serial each,
// 32 per wave in R9, unhidable at 1 block/CU with 4 waves/SIMD).
// R10 removes them:
//  - TWO-PHASE compaction everywhere: phase A counts passing keys per wave
//    with pure ballots (no memory), ONE atomicAdd per wave per sweep, one
//    shfl; phase B scatters with running ballot-popcount bases. s_topk slot
//    order is arbitrary (we only sum it) so cross-wave ordering is free.
//  - level-2 histogram build fused into sweep-1 (one fewer phase+barrier).
//  - s_cand LDS round-trip removed: candidates re-derived from register-
//    resident keys[] (sub-bin compaction + final scatter read keys again).
// Fallback radix path (cd > 1024, adversarial ties) retained unchanged.

#define TOPK 512
#define BT   1024
#define GRID 256
#define EPT  16                  // BT * EPT = 16384 >= n_neg
#define NHIST 8                  // pass-0 histogram copies (wave pairs)
#define CAP   1024               // max candidates for fast path
#define POS_LDS 1024
#define BCE_LO 1.0000005e-6f     // -log(1-1e-6)
#define BCE_HI 13.8155106f       // -log(1e-6)

__device__ __forceinline__ float decode_key(unsigned int ky) {
    unsigned int u = (ky >> 31) ? (ky ^ 0x80000000u) : (ky ^ 0xFFFFFFFFu);
    return __uint_as_float(u);
}

__global__ __launch_bounds__(BT, 4) void pauc_fused_kernel(
    const float* __restrict__ neg, int n_neg,
    const float* __restrict__ pos, int n_pos,
    float* __restrict__ out, float inv_denom, int k,
    float* __restrict__ partials, unsigned int* __restrict__ done) {
    const int tid  = threadIdx.x;
    const int lane = tid & 63;
    const int wv   = tid >> 6;

    __shared__ __align__(16) unsigned int hist[NHIST * 1024]; // 32 KB, pass-0
    __shared__ __align__(16) unsigned int hist2[1024];        // level-2 histogram
    __shared__ __align__(16) unsigned int cand2[1024 + 4];    // sub-bin cands (+pad)
    __shared__ float        s_topk[TOPK];
    __shared__ float        s_pos[POS_LDS];
    __shared__ unsigned int wtot[16];
    __shared__ unsigned int bc_digit, bc_kk, bc_cd;
    __shared__ unsigned int out_gt, out_cd2;
    __shared__ unsigned int sh_T, sh_g2;
    __shared__ float        s_red[BT / 64];

    const int rows_pb = (n_pos + GRID - 1) / GRID;      // 32 in harness
    const bool pos_in_lds = rows_pb <= POS_LDS;

    // -------- issue pos prefetch FIRST (latency hides under select) --------
    float pv0 = 0.0f;
    const int prow = blockIdx.x * rows_pb + tid;
    const bool pv0_v = pos_in_lds && (tid < rows_pb) && (prow < n_pos);
    if (pv0_v) pv0 = pos[prow];

    // ---------------- load all keys (every block, redundant) ----------------
    unsigned int keys[EPT];
    if (n_neg == BT * EPT) {                // harness case: float4 loads
        const float4* n4 = (const float4*)neg;
        #pragma unroll
        for (int t = 0; t < EPT / 4; ++t) {
            float4 v = n4[t * BT + tid];
            unsigned int u0 = __float_as_uint(v.x), u1 = __float_as_uint(v.y);
            unsigned int u2 = __float_as_uint(v.z), u3 = __float_as_uint(v.w);
            keys[4*t+0] = u0 ^ (0x80000000u | (unsigned)((int)u0 >> 31));
            keys[4*t+1] = u1 ^ (0x80000000u | (unsigned)((int)u1 >> 31));
            keys[4*t+2] = u2 ^ (0x80000000u | (unsigned)((int)u2 >> 31));
            keys[4*t+3] = u3 ^ (0x80000000u | (unsigned)((int)u3 >> 31));
        }
    } else {
        #pragma unroll
        for (int t = 0; t < EPT; ++t) {
            int i = t * BT + tid;
            unsigned int key = 0u;          // pad = smallest key
            if (i < n_neg) {
                unsigned int u = __float_as_uint(neg[i]);
                key = u ^ (0x80000000u | (unsigned)((int)u >> 31));
            }
            keys[t] = key;
        }
    }

    // zero histograms + counters (cand2 zeroed so pad slots are 0)
    #pragma unroll
    for (int i = 0; i < NHIST; ++i) hist[(i << 10) + tid] = 0u;
    hist2[tid] = 0u;
    cand2[tid] = 0u;
    if (tid < 4) cand2[1024 + tid] = 0u;
    if (tid == 0) { out_gt = 0u; out_cd2 = 0u; }
    if (pos_in_lds && tid < rows_pb) s_pos[tid] = pv0_v ? pv0 : 0.0f;
    __syncthreads();                                            // B1

    // ---------------- pass 0: privatized 10-bit histogram (copy/wave-pair) --
    {
        unsigned int* h = &hist[(unsigned)(wv >> 1) << 10];
        #pragma unroll
        for (int t = 0; t < EPT; ++t)
            atomicAdd(&h[keys[t] >> 22], 1u);
    }
    __syncthreads();                                            // B2

    // merge 8 copies (stride-1024: 2 lanes/bank -> free) + wave suffix scan
    unsigned int c = 0u;
    #pragma unroll
    for (int i = 0; i < NHIST; ++i) c += hist[(i << 10) + tid];
    unsigned int part = c;
    #pragma unroll
    for (int off = 1; off < 64; off <<= 1) {
        unsigned int v = __shfl_down(part, off, 64);
        if (lane + off < 64) part += v;
    }
    if (lane == 0) wtot[wv] = part;
    __syncthreads();                                            // B3
    // every wave redundantly suffix-scans the 16 wave totals (registers)
    unsigned int wsuf = 0u;
    #pragma unroll
    for (int w = 0; w < 16; ++w) wsuf += (w > wv) ? wtot[w] : 0u;
    const unsigned int k0 = (unsigned)k;
    unsigned int suf = part + wsuf;
    unsigned int s_next = __shfl_down(suf, 1, 64);
    if (lane == 63) s_next = wsuf;
    if (suf >= k0 && s_next < k0) {
        bc_digit = (unsigned)tid;
        bc_kk    = k0 - s_next;              // needed from chosen bin
        bc_cd    = c;                        // chosen bin's count
    }
    __syncthreads();                                            // B4

    const unsigned int B  = bc_digit;
    unsigned int kkv      = bc_kk;
    const unsigned int cd = bc_cd;

    if (cd <= CAP) {
        // ===== FAST PATH: two-phase scatter + fused level-2 histogram ======
        // sweep-1 phase A: per-wave count of bin>B keys (pure ballots) and
        // level-2 histogram of the bin==B keys (<=cd scattered atomics).
        unsigned int gcnt = 0u;
        #pragma unroll
        for (int t = 0; t < EPT; ++t) {
            unsigned int ky  = keys[t];
            unsigned int bin = ky >> 22;
            unsigned long long m = __ballot(bin > B);
            gcnt += (unsigned)__popcll(m);
            if (bin == B)
                atomicAdd(&hist2[(ky >> 12) & 1023u], 1u);
        }
        unsigned int gbase = 0u;
        if (lane == 0) gbase = atomicAdd(&out_gt, gcnt);   // ONE atomic/wave
        gbase = __shfl(gbase, 0, 64);
        // sweep-1 phase B: scatter with running ballot-popcount base
        #pragma unroll
        for (int t = 0; t < EPT; ++t) {
            unsigned int ky = keys[t];
            bool g = (ky >> 22) > B;
            unsigned long long m = __ballot(g);
            if (g) {
                unsigned int idx = gbase +
                    (unsigned)__popcll(m & ((1ull << lane) - 1ull));
                s_topk[idx] = decode_key(ky);
            }
            gbase += (unsigned)__popcll(m);
        }
        __syncthreads();                                        // B5

        unsigned int Tkey  = 0u;
        unsigned int n_tie = 0u;
        const bool all_sel = (kkv == cd);    // whole bin selected
        if (!all_sel) {
            // ---- scan level-2 histogram (built during sweep-1) ----
            unsigned int c2 = hist2[tid];
            unsigned int p2 = c2;
            #pragma unroll
            for (int off = 1; off < 64; off <<= 1) {
                unsigned int v = __shfl_down(p2, off, 64);
                if (lane + off < 64) p2 += v;
            }
            if (lane == 0) wtot[wv] = p2;
            __syncthreads();                                    // B6
            unsigned int ws2 = 0u;
            #pragma unroll
            for (int w = 0; w < 16; ++w) ws2 += (w > wv) ? wtot[w] : 0u;
            unsigned int sf2 = p2 + ws2;
            unsigned int sn2 = __shfl_down(sf2, 1, 64);
            if (lane == 63) sn2 = ws2;
            if (sf2 >= kkv && sn2 < kkv) {
                bc_digit = (unsigned)tid;    // reuse (level-1 values consumed)
                bc_kk    = kkv - sn2;
                bc_cd    = c2;
            }
            __syncthreads();                                    // B7
            const unsigned int B2   = bc_digit;
            const unsigned int kkv2 = bc_kk;
            const unsigned int cd2  = bc_cd;
            const bool all2 = (kkv2 == cd2);
            if (!all2) {
                // compact sub-bin candidates from register keys (expected
                // 1-3; ballot usually 0 -> near-free)
                #pragma unroll
                for (int t = 0; t < EPT; ++t) {
                    unsigned int ky = keys[t];
                    bool e2 = ((ky >> 22) == B) &&
                              (((ky >> 12) & 1023u) == B2);
                    unsigned long long m2 = __ballot(e2);
                    if (m2) {
                        unsigned int cnt = (unsigned)__popcll(m2);
                        unsigned int base;
                        if (lane == 0) base = atomicAdd(&out_cd2, cnt);
                        base = __shfl(base, 0, 64);
                        if (e2) {
                            unsigned int idx = base +
                                (unsigned)__popcll(m2 & ((1ull << lane) - 1ull));
                            cand2[idx] = ky;
                        }
                    }
                }
                __syncthreads();                                // B8
                // tiny rank-count: gt=#cand2>y, ge=#cand2>=y (broadcast
                // uint4; zero pads never raise gt; participants have y>0)
                unsigned int y = (tid < (int)cd2) ? cand2[tid] : 0u;
                unsigned int gt = 0u, ge = 0u;
                const uint4* c4 = (const uint4*)cand2;
                const int nq = (int)((cd2 + 3u) >> 2);
                for (int j = 0; j < nq; ++j) {
                    uint4 q = c4[j];
                    gt += (unsigned)(q.x > y) + (unsigned)(q.y > y)
                        + (unsigned)(q.z > y) + (unsigned)(q.w > y);
                    ge += (unsigned)(q.x >= y) + (unsigned)(q.y >= y)
                        + (unsigned)(q.z >= y) + (unsigned)(q.w >= y);
                }
                if (tid < (int)cd2 && gt < kkv2 && ge >= kkv2) {
                    sh_T = y; sh_g2 = gt;
                }
                __syncthreads();                                // B9
                Tkey  = sh_T;
                n_tie = kkv2 - sh_g2;
            } else {
                // whole sub-bin selected: T just below sub-bin, no ties.
                // (B,B2)==(0,0) with all2 would imply kkv==cd (all_sel).
                Tkey  = ((B << 22) | (B2 << 12)) - 1u;
                n_tie = 0u;
            }
        }
        // final in-bin scatter, two-phase (sel count = kkv - n_tie; ranges
        // from out_gt are disjoint regardless of wave interleaving)
        unsigned int scnt = 0u;
        #pragma unroll
        for (int t = 0; t < EPT; ++t) {
            unsigned int ky = keys[t];
            bool sel = ((ky >> 22) == B) && (all_sel || ky > Tkey);
            unsigned long long m = __ballot(sel);
            scnt += (unsigned)__popcll(m);
        }
        unsigned int sbase = 0u;
        if (lane == 0) sbase = atomicAdd(&out_gt, scnt);   // ONE atomic/wave
        sbase = __shfl(sbase, 0, 64);
        #pragma unroll
        for (int t = 0; t < EPT; ++t) {
            unsigned int ky = keys[t];
            bool sel = ((ky >> 22) == B) && (all_sel || ky > Tkey);
            unsigned long long m = __ballot(sel);
            if (sel) {
                unsigned int idx = sbase +
                    (unsigned)__popcll(m & ((1ull << lane) - 1ull));
                s_topk[idx] = decode_key(ky);
            }
            sbase += (unsigned)__popcll(m);
        }
        if ((unsigned)tid < n_tie)
            s_topk[k0 - n_tie + tid] = decode_key(Tkey);
    } else {
        // ============ FALLBACK: classic radix passes on low 22 bits ========
        unsigned int prefix = B << 22;
        unsigned int pmask  = 0xFFC00000u;
        const int      shifts2[3] = {12, 2, 0};
        const unsigned nbv2[3]    = {1024u, 1024u, 4u};
        for (int pass = 0; pass < 3; ++pass) {
            const int shift      = shifts2[pass];
            const unsigned nb    = nbv2[pass];
            const unsigned dmask = nb - 1u;
            if (tid < (int)nb) hist[tid] = 0u;
            __syncthreads();
            #pragma unroll
            for (int t = 0; t < EPT; ++t) {
                unsigned int ky = keys[t];
                if ((ky & pmask) == prefix)
                    atomicAdd(&hist[(ky >> shift) & dmask], 1u);
            }
            __syncthreads();
            unsigned int cc = (tid < (int)nb) ? hist[tid] : 0u;
            unsigned int p2 = cc;
            #pragma unroll
            for (int off = 1; off < 64; off <<= 1) {
                unsigned int v = __shfl_down(p2, off, 64);
                if (lane + off < 64) p2 += v;
            }
            if (lane == 0) wtot[wv] = p2;
            __syncthreads();
            unsigned int ws2 = 0u;
            #pragma unroll
            for (int w = 0; w < 16; ++w) ws2 += (w > wv) ? wtot[w] : 0u;
            unsigned int sf = p2 + ws2;
            unsigned int sn = __shfl_down(sf, 1, 64);
            if (lane == 63) sn = ws2;
            if (tid < (int)nb && sf >= kkv && sn < kkv) {
                bc_digit = (unsigned)tid;
                bc_kk    = kkv - sn;
                bc_cd    = cc;
            }
            __syncthreads();
            unsigned int newpref = prefix | (bc_digit << shift);
            if (pass < 2 && bc_kk == bc_cd && newpref != 0u) {
                prefix = newpref - 1u;       // whole bin: T below bin, no ties
                kkv = 0u;
                break;
            }
            prefix = newpref;
            kkv = bc_kk;
            pmask |= dmask << shift;
        }
        const unsigned int T = prefix;
        #pragma unroll
        for (int t = 0; t < EPT; ++t) {
            unsigned int ky = keys[t];
            bool g = ky > T;
            unsigned long long m = __ballot(g);
            if (m) {
                unsigned int cnt = (unsigned)__popcll(m);
                unsigned int base;
                if (lane == 0) base = atomicAdd(&out_gt, cnt);
                base = __shfl(base, 0, 64);
                if (g) {
                    unsigned int idx = base +
                        (unsigned)__popcll(m & ((1ull << lane) - 1ull));
                    s_topk[idx] = decode_key(ky);
                }
            }
        }
        if ((unsigned)tid < kkv)
            s_topk[(k0 - kkv) + tid] = decode_key(T);
    }
    __syncthreads();                                            // B10

    // -------- bce partial sum: 1 col/thread, 2 row-groups from LDS ----------
    const int col = tid & (TOPK - 1);
    const int rg  = tid >> 9;                          // 0 or 1
    const bool cv = col < k;
    const float tv = cv ? s_topk[col] : 0.0f;
    const int rpg  = (rows_pb + (BT / TOPK) - 1) / (BT / TOPK);  // 16
    const int rbase = blockIdx.x * rows_pb + rg * rpg;
    int lim = n_pos - rbase;
    int lmax = rows_pb - rg * rpg;
    if (lim > lmax) lim = lmax;
    if (lim > rpg)  lim = rpg;
    if (lim < 0)    lim = 0;
    float acc = 0.0f;
    if (pos_in_lds) {
        const float* sp = &s_pos[rg * rpg];
        #pragma unroll 4
        for (int r = 0; r < lim; ++r) {
            float pv = sp[r];
            // -log(clip(sigmoid(pv - tv))) = clamp(log(1 + exp(tv - pv)))
            float b = __logf(1.0f + __expf(tv - pv));
            b = fminf(fmaxf(b, BCE_LO), BCE_HI);
            acc += b;
        }
    } else {
        for (int r = 0; r < lim; ++r) {
            float pv = pos[rbase + r];
            float b = __logf(1.0f + __expf(tv - pv));
            b = fminf(fmaxf(b, BCE_LO), BCE_HI);
            acc += b;
        }
    }
    if (!cv) acc = 0.0f;
    #pragma unroll
    for (int off = 32; off > 0; off >>= 1) acc += __shfl_down(acc, off, 64);
    if (lane == 0) s_red[wv] = acc;
    __syncthreads();                                            // B11
    if (tid == 0) {
        float t = 0.0f;
        #pragma unroll
        for (int w = 0; w < BT / 64; ++w) t += s_red[w];
        __hip_atomic_store(&partials[blockIdx.x], t,
                           __ATOMIC_RELAXED, __HIP_MEMORY_SCOPE_AGENT);
        __hip_atomic_store(&done[blockIdx.x], 1u,
                           __ATOMIC_RELEASE, __HIP_MEMORY_SCOPE_AGENT);
    }

    // ---------------- block 0: gather the 256 partials ----------------------
    if (blockIdx.x == 0) {
        float a = 0.0f;
        if (tid < GRID) {
            while (__hip_atomic_load(&done[tid], __ATOMIC_RELAXED,
                                     __HIP_MEMORY_SCOPE_AGENT) != 1u)
                __builtin_amdgcn_s_sleep(1);
            __builtin_amdgcn_fence(__ATOMIC_ACQUIRE, "agent");
            a = __hip_atomic_load(&partials[tid], __ATOMIC_RELAXED,
                                  __HIP_MEMORY_SCOPE_AGENT);
        }
        #pragma unroll
        for (int off = 32; off > 0; off >>= 1) a += __shfl_down(a, off, 64);
        if (lane == 0) s_red[wv] = a;
        __syncthreads();
        if (tid == 0) {
            float t = 0.0f;
            #pragma unroll
            for (int w = 0; w < BT / 64; ++w) t += s_red[w];
            out[0] = t * inv_denom;
        }
    }
}

extern "C" void kernel_launch(void* const* d_in, const int* in_sizes, int n_in,
                              void* d_out, int out_size, void* d_ws, size_t ws_size,
                              hipStream_t stream) {
    const float* neg = (const float*)d_in[0];   // score_neg, 16384
    const float* pos = (const float*)d_in[1];   // score_pos, 8192
    const int n_neg = in_sizes[0];
    const int n_pos = in_sizes[1];
    float* out = (float*)d_out;
    float* ws  = (float*)d_ws;

    int k = TOPK; if (k > n_neg) k = n_neg;
    float*        partials = ws;                             // [0, GRID)
    unsigned int* done     = (unsigned int*)(ws + GRID);     // [GRID, 2*GRID)

    const float inv_denom = (float)(1.0 / ((double)n_pos * (double)n_neg));
    pauc_fused_kernel<<<GRID, BT, 0, stream>>>(
        neg, n_neg, pos, n_pos, out, inv_denom, k, partials, done);
}